// Round 3
// baseline (116.585 us; speedup 1.0000x reference)
//
#include <hip/hip_runtime.h>

// IMPACT modality argmin, item-sorted + 4-query ILP + XCD-chunked blocks.
//
// Pipeline (all on `stream`):
//   1. memsetAsync hist=0
//   2. hist_kernel:    hist[item] += 1 over all queries
//   3. scan_kernel:    cursor = exclusive prefix sum of hist (1 block)
//   4. scatter_kernel: perm[atomicAdd(cursor[item])] = query  (groups by item)
//   5. main kernel:    16-lane group processes 4 CONSECUTIVE sorted queries
//                      (usually same item -> shared v-rows in L1; 4 indep
//                      dependency chains -> latency hiding), block index
//                      chunk-mapped so adjacent blocks share an XCD L2.
//
// Distances accumulated in f64 of exact f32 diffs so the argmin matches the
// f32 numpy reference ordering (absmax 0.0 in rounds 1-2).

#define M_TOT 14
#define CDIM 128
#define QPG 4          // queries per 16-lane group

__global__ void impact_hist(const int* __restrict__ item_ids,
                            int* __restrict__ hist, int B) {
    int i = blockIdx.x * blockDim.x + threadIdx.x;
    if (i < B) atomicAdd(&hist[item_ids[i]], 1);
}

__global__ __launch_bounds__(1024) void impact_scan(const int* __restrict__ hist,
                                                    int* __restrict__ cursor, int n) {
    __shared__ int partial[1024];
    int tid = threadIdx.x;
    int ch = (n + 1023) >> 10;
    int base = tid * ch;
    int s = 0;
    for (int j = 0; j < ch; ++j) {
        int k = base + j;
        if (k < n) s += hist[k];
    }
    partial[tid] = s;
    __syncthreads();
    for (int off = 1; off < 1024; off <<= 1) {
        int v = (tid >= off) ? partial[tid - off] : 0;
        __syncthreads();
        partial[tid] += v;
        __syncthreads();
    }
    int run = (tid > 0) ? partial[tid - 1] : 0;
    for (int j = 0; j < ch; ++j) {
        int k = base + j;
        if (k < n) { cursor[k] = run; run += hist[k]; }
    }
}

__global__ void impact_scatter(const int* __restrict__ item_ids,
                               int* __restrict__ cursor,
                               int* __restrict__ perm, int B) {
    int i = blockIdx.x * blockDim.x + threadIdx.x;
    if (i < B) {
        int pos = atomicAdd(&cursor[item_ids[i]], 1);
        perm[pos] = i;
    }
}

__global__ __launch_bounds__(256) void impact_main(
    const int* __restrict__ user_ids,
    const int* __restrict__ item_ids,
    const float* __restrict__ users_emb,   // [USER_N, 128]
    const float* __restrict__ item_emb,    // [ITEM_N*14, 128]
    const int* __restrict__ nb_mod,        // [ITEM_N]
    const int* __restrict__ perm,          // may be null (unsorted fallback)
    float* __restrict__ out,
    int B)
{
    // chunked XCD mapping: consecutive logical blocks -> same XCD L2
    int p = blockIdx.x;
    int lb = p;
    if ((gridDim.x & 7) == 0) {
        int cpx = gridDim.x >> 3;
        lb = (p & 7) * cpx + (p >> 3);
    }

    int g = threadIdx.x >> 4;   // 16 groups per block
    int l = threadIdx.x & 15;
    int i0 = (lb * 16 + g) * QPG;   // 64 queries per block

    bool  valid[QPG];
    int   q[QPG], nb[QPG], bidx[QPG];
    float4 u0[QPG], u1[QPG];
    const float4* ib[QPG];
    double best[QPG];
    int mmax = 0;

#pragma unroll
    for (int j = 0; j < QPG; ++j) {
        int iq = i0 + j;
        valid[j] = iq < B;
        q[j] = valid[j] ? (perm ? perm[iq] : iq) : 0;
        int uid = valid[j] ? user_ids[q[j]] : 0;
        int iid = valid[j] ? item_ids[q[j]] : 0;
        nb[j]  = valid[j] ? nb_mod[iid] : 0;
        if (valid[j] && nb[j] > mmax) mmax = nb[j];
        const float4* urow = (const float4*)(users_emb + (size_t)uid * CDIM);
        u0[j] = urow[l];
        u1[j] = urow[l + 16];
        ib[j] = (const float4*)(item_emb + ((size_t)iid * M_TOT + 1) * CDIM);
        best[j] = 1e300;
        bidx[j] = 1;
    }

    for (int m = 1; m <= mmax; ++m) {
#pragma unroll
        for (int j = 0; j < QPG; ++j) {
            if (valid[j] && m <= nb[j]) {
                const float4* vrow = ib[j] + (size_t)(m - 1) * (CDIM / 4);
                float4 v0 = vrow[l];
                float4 v1 = vrow[l + 16];
                float d;
                double s = 0.0;
                d = u0[j].x - v0.x; s += (double)d * d;
                d = u0[j].y - v0.y; s += (double)d * d;
                d = u0[j].z - v0.z; s += (double)d * d;
                d = u0[j].w - v0.w; s += (double)d * d;
                d = u1[j].x - v1.x; s += (double)d * d;
                d = u1[j].y - v1.y; s += (double)d * d;
                d = u1[j].z - v1.z; s += (double)d * d;
                d = u1[j].w - v1.w; s += (double)d * d;
                // 16-lane butterfly (xor < 16 stays in group; condition is
                // group-uniform so all 16 participants are active)
                s += __shfl_xor(s, 1);
                s += __shfl_xor(s, 2);
                s += __shfl_xor(s, 4);
                s += __shfl_xor(s, 8);
                if (s < best[j]) { best[j] = s; bidx[j] = m; }
            }
        }
    }

    if (l == 0) {
#pragma unroll
        for (int j = 0; j < QPG; ++j)
            if (valid[j])
                out[q[j]] = (float)(bidx[j] - 1) / (float)(nb[j] - 1) + 1.0f;
    }
}

extern "C" void kernel_launch(void* const* d_in, const int* in_sizes, int n_in,
                              void* d_out, int out_size, void* d_ws, size_t ws_size,
                              hipStream_t stream) {
    // inputs: 0 user_ids, 1 item_ids, 2 concept_ids (unused),
    //         3 users_emb_weight, 4 item_resp_emb_weight,
    //         5 mask (unused; nb_modalities carries the same info), 6 nb_modalities
    const int*   user_ids  = (const int*)d_in[0];
    const int*   item_ids  = (const int*)d_in[1];
    const float* users_emb = (const float*)d_in[3];
    const float* item_emb  = (const float*)d_in[4];
    const int*   nb_mod    = (const int*)d_in[6];
    float* out = (float*)d_out;

    int B = in_sizes[0];
    int n_items = in_sizes[6];

    // ws layout: hist[n_items] | cursor[n_items] | perm[B]
    size_t need = ((size_t)n_items * 2 + (size_t)B) * sizeof(int);
    int* perm = nullptr;

    if (ws_size >= need) {
        int* hist   = (int*)d_ws;
        int* cursor = hist + n_items;
        perm        = cursor + n_items;

        hipMemsetAsync(hist, 0, (size_t)n_items * sizeof(int), stream);
        impact_hist<<<(B + 255) / 256, 256, 0, stream>>>(item_ids, hist, B);
        impact_scan<<<1, 1024, 0, stream>>>(hist, cursor, n_items);
        impact_scatter<<<(B + 255) / 256, 256, 0, stream>>>(item_ids, cursor, perm, B);
    }

    int qpb = 16 * QPG;                 // 64 queries per block
    int grid = (B + qpb - 1) / qpb;
    impact_main<<<grid, 256, 0, stream>>>(
        user_ids, item_ids, users_emb, item_emb, nb_mod, perm, out, B);
}